// Round 10
// baseline (19308.127 us; speedup 1.0000x reference)
//
#include <hip/hip_runtime.h>

// Problem constants
#define S_TOTAL 19648      // B*N sequential LSTM steps
#define T_CH    12         // chains = MFMA N dimension (padded to 16)
#define HID     128
#define NT      512        // 8 waves per block
#define NBLK    256        // block 0 = LSTM, blocks 1..255 = clock heaters
#define FLAG_MAGIC 0x600DD00Du
#define SPIN_CAP   120000  // backstop only; normal exit is the done-flag

typedef _Float16 half8 __attribute__((ext_vector_type(8)));
typedef _Float16 half2v __attribute__((ext_vector_type(2)));
typedef float f4 __attribute__((ext_vector_type(4)));

__device__ __forceinline__ float fast_sigmoid(float v) {
    return __builtin_amdgcn_rcpf(1.0f + __expf(-v));
}
__device__ __forceinline__ float fast_tanh(float v) {
    return 2.0f * __builtin_amdgcn_rcpf(1.0f + __expf(-2.0f * v)) - 1.0f;
}
__device__ __forceinline__ float fdot2(half2v a, half2v b, float c) {
    return __builtin_amdgcn_fdot2(a, b, c, false);
}

// ---------------------------------------------------------------------------
// R9 post-mortem: R8 and R9 produced BIT-IDENTICAL absmax (9.741211e-2)
// despite different ext-MFMA intrinsics -> the recurrence was identical and
// correct; the bug is in a change shared by R8/R9 (out-from-B-frags path /
// epilogue / heaters). R10 therefore reverts to the EXACT R7 kernel
// (passed: absmax 4.88e-4, 18.9 ms) and adds ONLY the heater wrapper, to
// test the DVFS hypothesis with a known-good numeric core:
// three structurally different kernels (VALU-, DS-, MFMA-bound) all plateau
// at ~19 ms with 3x replay variance on identical graphs — clock state, not
// pipes. 256 blocks on 256 CUs => round-robin gives block 0 its own CU.
// ---------------------------------------------------------------------------
__global__ __launch_bounds__(NT, 2) void lstm_mfma(
    const float* __restrict__ x,      // (S,3,12): s*36 + f*12 + t
    const float* __restrict__ W_ih,   // (512,3)
    const float* __restrict__ W_hh,   // (512,128)
    const float* __restrict__ b_ih,   // (512)
    const float* __restrict__ b_hh,   // (512)
    const float* __restrict__ W_lin,  // (128)
    const float* __restrict__ b_lin,  // (1)
    float* __restrict__ out,          // (S,12): s*12 + t
    unsigned* __restrict__ ws)        // ws[0] = done flag
{
    const int tid = threadIdx.x;

    // ---------------- heater blocks: pin the clock, then exit ----------------
    if (blockIdx.x != 0) {
        float r0 = 1.0f + (float)tid * 1e-7f;
        float r1 = 1.1f, r2 = 1.2f, r3 = 1.3f;
        for (int it = 0; it < SPIN_CAP; ++it) {
#pragma unroll
            for (int u = 0; u < 64; ++u) {
                r0 = __builtin_fmaf(r0, 1.0000001f, 1e-9f);
                r1 = __builtin_fmaf(r1, 0.9999999f, 1e-9f);
                r2 = __builtin_fmaf(r2, 1.0000002f, -1e-9f);
                r3 = __builtin_fmaf(r3, 0.9999998f, -1e-9f);
            }
            if (__hip_atomic_load(ws, __ATOMIC_RELAXED,
                                  __HIP_MEMORY_SCOPE_AGENT) == FLAG_MAGIC)
                break;
        }
        if (r0 + r1 + r2 + r3 > 1e30f && tid == 0)   // DCE guard, never true
            ((float*)ws)[8] = r0;
        return;
    }

    // ---------------- block 0: the LSTM recurrence (R7 verbatim) ----------------
    const int w   = tid >> 6;    // wave 0..7  -> j-tile base 16w
    const int l   = tid & 63;
    const int n   = l & 15;      // chain (B/C/D col); for A, l&15 is row m
    const int qk  = l >> 4;      // k-quad / row-quad

    // hfrag[buf][kt][lane][8 fp16]: element [kt][g*16+n][e] = h[kt*32+g*8+e][n]
    __shared__ __align__(16) _Float16 hfrag[2][4][64][8];   // 8 KB
    __shared__ float pout[2][16][8];                        // partial out sums

    // ---- load A fragments (W_hh -> fp16, once) ----
    half8 A[4][4];
    half8 Aext[4];
#pragma unroll
    for (int q = 0; q < 4; ++q) {
        const int row = q * HID + 16 * w + (l & 15);
#pragma unroll
        for (int kt = 0; kt < 4; ++kt) {
            const float* src = &W_hh[row * HID + kt * 32 + qk * 8];
            half8 a;
#pragma unroll
            for (int e = 0; e < 8; ++e) a[e] = (_Float16)src[e];
            A[q][kt] = a;
        }
        half8 ae = {};   // ext tile: k=0..3 live on qk==0 lanes only
        if (qk == 0) {
            ae[0] = (_Float16)W_ih[row * 3 + 0];
            ae[1] = (_Float16)W_ih[row * 3 + 1];
            ae[2] = (_Float16)W_ih[row * 3 + 2];
            ae[3] = (_Float16)(b_ih[row] + b_hh[row]);
        }
        Aext[q] = ae;
    }

    // W_lin pairs for this lane's 4 output rows j0..j0+3 (j0 = 16w + 4qk)
    const int j0 = 16 * w + 4 * qk;
    half2v wl01, wl23;
    wl01[0] = (_Float16)W_lin[j0];     wl01[1] = (_Float16)W_lin[j0 + 1];
    wl23[0] = (_Float16)W_lin[j0 + 2]; wl23[1] = (_Float16)W_lin[j0 + 3];
    const float blin = b_lin[0];

    // Persistent B-ext: k=3 slot = 1.0 (bias) on qk==0 lanes, chains 0..11
    half8 Bext = {};
    if (qk == 0 && n < T_CH) Bext[3] = (_Float16)1.0f;

    // ---- zero LDS ----
    ((uint4*)hfrag)[tid] = make_uint4(0, 0, 0, 0);   // 512 * 16B = 8 KB
    if (tid < 256) ((float*)pout)[tid] = 0.0f;

    // cell state for this lane's 4 (j, chain=n) cells
    float c0 = 0.f, c1 = 0.f, c2 = 0.f, c3 = 0.f;

    // x prefetch for s=0
    float xf0 = 0.f, xf1 = 0.f, xf2 = 0.f;
    if (qk == 0 && n < T_CH) { xf0 = x[n]; xf1 = x[12 + n]; xf2 = x[24 + n]; }

    __syncthreads();

    for (int s = 0; s < S_TOTAL; ++s) {
        const int p = s & 1;

        // Bext <- x_s (k=0..2 slots)
        if (qk == 0 && n < T_CH) {
            Bext[0] = (_Float16)xf0;
            Bext[1] = (_Float16)xf1;
            Bext[2] = (_Float16)xf2;
        }
        // prefetch x for s+1 (L2-resident; vmcnt drain hidden behind step)
        {
            const int sn = (s + 1 < S_TOTAL) ? (s + 1) : s;
            if (qk == 0 && n < T_CH) {
                xf0 = x[sn * 36 + n];
                xf1 = x[sn * 36 + 12 + n];
                xf2 = x[sn * 36 + 24 + n];
            }
        }

        // ---- read B fragments (h_{s-1}) : 4x ds_read_b128, broadcast in wave ----
        const half8 B0 = *(const half8*)&hfrag[p][0][l][0];
        const half8 B1 = *(const half8*)&hfrag[p][1][l][0];
        const half8 B2 = *(const half8*)&hfrag[p][2][l][0];
        const half8 B3 = *(const half8*)&hfrag[p][3][l][0];

        // ---- Z = Wext.[x;1] + Whh.h  (per wave: 4 gate accum tiles) ----
        const f4 z = {0.f, 0.f, 0.f, 0.f};
        f4 ac0 = __builtin_amdgcn_mfma_f32_16x16x32_f16(Aext[0], Bext, z, 0, 0, 0);
        f4 ac1 = __builtin_amdgcn_mfma_f32_16x16x32_f16(Aext[1], Bext, z, 0, 0, 0);
        f4 ac2 = __builtin_amdgcn_mfma_f32_16x16x32_f16(Aext[2], Bext, z, 0, 0, 0);
        f4 ac3 = __builtin_amdgcn_mfma_f32_16x16x32_f16(Aext[3], Bext, z, 0, 0, 0);
#pragma unroll
        for (int kt = 0; kt < 4; ++kt) {
            const half8 B = (kt == 0) ? B0 : (kt == 1) ? B1 : (kt == 2) ? B2 : B3;
            ac0 = __builtin_amdgcn_mfma_f32_16x16x32_f16(A[0][kt], B, ac0, 0, 0, 0);
            ac1 = __builtin_amdgcn_mfma_f32_16x16x32_f16(A[1][kt], B, ac1, 0, 0, 0);
            ac2 = __builtin_amdgcn_mfma_f32_16x16x32_f16(A[2][kt], B, ac2, 0, 0, 0);
            ac3 = __builtin_amdgcn_mfma_f32_16x16x32_f16(A[3][kt], B, ac3, 0, 0, 0);
        }

        // ---- in-lane gate nonlinearities + c/h update (4 cells) ----
        float h0, h1, h2, h3;
        {
            const float i0 = fast_sigmoid(ac0[0]), f0 = fast_sigmoid(ac1[0]);
            const float g0 = fast_tanh(ac2[0]),    o0 = fast_sigmoid(ac3[0]);
            c0 = __builtin_fmaf(f0, c0, i0 * g0);  h0 = o0 * fast_tanh(c0);
            const float i1 = fast_sigmoid(ac0[1]), f1 = fast_sigmoid(ac1[1]);
            const float g1 = fast_tanh(ac2[1]),    o1 = fast_sigmoid(ac3[1]);
            c1 = __builtin_fmaf(f1, c1, i1 * g1);  h1 = o1 * fast_tanh(c1);
            const float i2 = fast_sigmoid(ac0[2]), f2 = fast_sigmoid(ac1[2]);
            const float g2 = fast_tanh(ac2[2]),    o2 = fast_sigmoid(ac3[2]);
            c2 = __builtin_fmaf(f2, c2, i2 * g2);  h2 = o2 * fast_tanh(c2);
            const float i3 = fast_sigmoid(ac0[3]), f3 = fast_sigmoid(ac1[3]);
            const float g3 = fast_tanh(ac2[3]),    o3 = fast_sigmoid(ac3[3]);
            c3 = __builtin_fmaf(f3, c3, i3 * g3);  h3 = o3 * fast_tanh(c3);
        }

        // pack h pairs (k ascending): (h0,h1), (h2,h3)
        half2v hp01, hp23;
        hp01[0] = (_Float16)h0; hp01[1] = (_Float16)h1;
        hp23[0] = (_Float16)h2; hp23[1] = (_Float16)h3;

        // ---- output partial: this lane's contribution for chain n ----
        float pp = fdot2(hp23, wl23, fdot2(hp01, wl01, 0.0f));
        pp += __shfl_xor(pp, 16, 64);
        pp += __shfl_xor(pp, 32, 64);
        if (qk == 0) pout[p][n][w] = pp;      // per-wave partial for chain n

        // ---- wave 7: combine LAST step's partials -> out[s-1] ----
        if (w == 7 && l < T_CH && s > 0) {
            const f4 pa = *(const f4*)&pout[p ^ 1][l][0];
            const f4 pb = *(const f4*)&pout[p ^ 1][l][4];
            out[(s - 1) * T_CH + l] =
                pa.x + pa.y + pa.z + pa.w + pb.x + pb.y + pb.z + pb.w + blin;
        }

        // ---- write h_s to the other buffer in B-frag order ----
        // j = j0 + r (r=0..3): kt = w>>1; lane-group g = 2*(w&1) + (qk>>1);
        // elem = 4*(qk&1) + r. Data = k-ascending pairs (hp01, hp23).
        {
            const int ktw = w >> 1;
            const int lp  = (2 * (w & 1) + (qk >> 1)) * 16 + n;
            half2v* dst = (half2v*)&hfrag[p ^ 1][ktw][lp][4 * (qk & 1)];
            dst[0] = hp01;
            dst[1] = hp23;
        }

        __syncthreads();   // h_s / partials visible; buffers swap next step
    }

    // ---- drain: out[S-1] ----
    if (w == 7 && l < T_CH) {
        const int pb2 = (S_TOTAL - 1) & 1;
        const f4 pa = *(const f4*)&pout[pb2][l][0];
        const f4 pb = *(const f4*)&pout[pb2][l][4];
        out[(S_TOTAL - 1) * T_CH + l] =
            pa.x + pa.y + pa.z + pa.w + pb.x + pb.y + pb.z + pb.w + blin;
    }

    // ---- release the heaters ----
    if (tid == 0)
        __hip_atomic_store(ws, FLAG_MAGIC, __ATOMIC_RELAXED,
                           __HIP_MEMORY_SCOPE_AGENT);
}

extern "C" void kernel_launch(void* const* d_in, const int* in_sizes, int n_in,
                              void* d_out, int out_size, void* d_ws, size_t ws_size,
                              hipStream_t stream) {
    const float* x     = (const float*)d_in[0];
    const float* W_ih  = (const float*)d_in[1];
    const float* W_hh  = (const float*)d_in[2];
    const float* b_ih  = (const float*)d_in[3];
    const float* b_hh  = (const float*)d_in[4];
    const float* W_lin = (const float*)d_in[5];
    const float* b_lin = (const float*)d_in[6];
    float* out = (float*)d_out;

    hipLaunchKernelGGL(lstm_mfma, dim3(NBLK), dim3(NT), 0, stream,
                       x, W_ih, W_hh, b_ih, b_hh, W_lin, b_lin, out,
                       (unsigned*)d_ws);
}

// Round 11
// 18425.999 us; speedup vs baseline: 1.0479x; 1.0479x over previous
//
#include <hip/hip_runtime.h>

// Problem constants
#define S_TOTAL 19648      // B*N sequential LSTM steps
#define T_CH    12         // chains = MFMA N dimension (padded to 16)
#define HID     128
#define NT      512        // 8 waves, one block (grid = 1)

typedef _Float16 half8  __attribute__((ext_vector_type(8)));
typedef _Float16 half4v __attribute__((ext_vector_type(4)));
typedef _Float16 half2v __attribute__((ext_vector_type(2)));
typedef float f4 __attribute__((ext_vector_type(4)));

#define NLOG2E  (-1.4426950408889634f)   // -log2(e): folded into i,f,o rows
#define N2LOG2E (-2.8853900817779268f)   // -2log2(e): folded into g rows

#if __has_builtin(__builtin_amdgcn_exp2f)
#define EXP2(x) __builtin_amdgcn_exp2f(x)
#else
#define EXP2(x) __expf((x) * 0.69314718055994531f)
#endif

// z pre-scaled by -log2e -> sigmoid(orig z)
__device__ __forceinline__ float sigz(float z) {
    return __builtin_amdgcn_rcpf(1.0f + EXP2(z));
}
// z pre-scaled by -2log2e -> tanh(orig z)
__device__ __forceinline__ float tanz(float z) {
    return __builtin_fmaf(2.0f, __builtin_amdgcn_rcpf(1.0f + EXP2(z)), -1.0f);
}
__device__ __forceinline__ float fdot2(half2v a, half2v b, float c) {
    return __builtin_amdgcn_fdot2(a, b, c, false);
}

// ---------------------------------------------------------------------------
// R10 post-mortem: heaters ran (chip VALUBusy 128) and dur was unchanged ->
// DVFS falsified. Counters say VALU-issue-bound: ~1420 VALU cyc/SIMD/step of
// which 640 = quarter-rate transcendental floor; the rest is per-step Bext
// register insertion, address recomputation, pre-scale muls, store code.
// R11 keeps the R7-verified core (A/B/C mappings, pout mechanism, h-write)
// and removes "other VALU": (1) activation constants folded into weights
// (exact); (2) x rides the 5th K-tile in LDS (no Bext register dance);
// (3) LDS addresses hoisted; (4) out stores batched via a 16-deep LDS ring,
// flushed coalesced every 8 steps (no per-step global store drain).
// ---------------------------------------------------------------------------
__global__ __launch_bounds__(NT, 2) void lstm_mfma(
    const float* __restrict__ x,      // (S,3,12): s*36 + f*12 + t
    const float* __restrict__ W_ih,   // (512,3)
    const float* __restrict__ W_hh,   // (512,128)
    const float* __restrict__ b_ih,   // (512)
    const float* __restrict__ b_hh,   // (512)
    const float* __restrict__ W_lin,  // (128)
    const float* __restrict__ b_lin,  // (1)
    float* __restrict__ out)          // (S,12): s*12 + t
{
    const int tid = threadIdx.x;
    const int w   = tid >> 6;    // wave 0..7 -> j-tile base 16w
    const int l   = tid & 63;
    const int n   = l & 15;      // chain (B/C/D col); for A, l&15 is row m
    const int qk  = l >> 4;      // k-quad / row-quad

    // hfrag[buf][kt][lane][8 fp16]; kt=4 is the ext tile:
    //   [4][n][0..2] = x0..x2 (chain n), [4][n][3] = 1.0 (bias), rest 0.
    __shared__ __align__(16) _Float16 hfrag[2][5][64][8];   // 10240 B
    __shared__ float pout[2][16][8];                        // partial out sums
    __shared__ __align__(16) float oring[16][T_CH];         // out ring buffer

    // ---- A fragments (W_hh / W_ih / bias -> fp16, scales folded) ----
    half8 A[4][5];
#pragma unroll
    for (int q = 0; q < 4; ++q) {
        const float sc = (q == 2) ? N2LOG2E : NLOG2E;
        const int row = q * HID + 16 * w + (l & 15);
#pragma unroll
        for (int kt = 0; kt < 4; ++kt) {
            const float* src = &W_hh[row * HID + kt * 32 + qk * 8];
            half8 a;
#pragma unroll
            for (int e = 0; e < 8; ++e) a[e] = (_Float16)(src[e] * sc);
            A[q][kt] = a;
        }
        half8 ae = {};   // ext tile: k=0..3 live on qk==0 lanes only
        if (qk == 0) {
            ae[0] = (_Float16)(W_ih[row * 3 + 0] * sc);
            ae[1] = (_Float16)(W_ih[row * 3 + 1] * sc);
            ae[2] = (_Float16)(W_ih[row * 3 + 2] * sc);
            ae[3] = (_Float16)((b_ih[row] + b_hh[row]) * sc);
        }
        A[q][4] = ae;
    }

    // W_lin pairs for this lane's 4 output rows j0..j0+3 (j0 = 16w + 4qk)
    const int j0 = 16 * w + 4 * qk;
    half2v wl01, wl23;
    wl01[0] = (_Float16)W_lin[j0];     wl01[1] = (_Float16)W_lin[j0 + 1];
    wl23[0] = (_Float16)W_lin[j0 + 2]; wl23[1] = (_Float16)W_lin[j0 + 3];
    const float blin = b_lin[0];

    // ---- zero LDS (hfrag = 640 uint4), then seed bias + x(s=0) ----
    ((uint4*)hfrag)[tid] = make_uint4(0, 0, 0, 0);
    if (tid < 128) ((uint4*)hfrag)[512 + tid] = make_uint4(0, 0, 0, 0);
    if (tid < 256) ((float*)pout)[tid] = 0.0f;
    __syncthreads();
    if (tid < 16) {
        hfrag[0][4][tid][3] = (_Float16)1.0f;
        hfrag[1][4][tid][3] = (_Float16)1.0f;
    }
    if (tid < T_CH) {
        hfrag[0][4][tid][0] = (_Float16)x[tid];
        hfrag[0][4][tid][1] = (_Float16)x[12 + tid];
        hfrag[0][4][tid][2] = (_Float16)x[24 + tid];
    }

    // ---- hoisted LDS addresses ----
    const _Float16* rb0 = &hfrag[0][0][l][0];
    const _Float16* rb1 = &hfrag[1][0][l][0];
    const int ktw = w >> 1;
    const int lp  = (2 * (w & 1) + (qk >> 1)) * 16 + n;
    _Float16* wb0 = &hfrag[0][ktw][lp][4 * (qk & 1)];
    _Float16* wb1 = &hfrag[1][ktw][lp][4 * (qk & 1)];

    float c0 = 0.f, c1 = 0.f, c2 = 0.f, c3 = 0.f;
    __syncthreads();

    for (int s = 0; s < S_TOTAL; ++s) {
        const int p = s & 1;
        const _Float16* rb = p ? rb1 : rb0;

        // wave 0: load x_{s+1} early (written to LDS late in the step)
        float xa = 0.f, xb = 0.f, xc = 0.f;
        if (w == 0 && l < T_CH) {
            const int sn = (s + 1 < S_TOTAL) ? (s + 1) : s;
            xa = x[sn * 36 + l];
            xb = x[sn * 36 + 12 + l];
            xc = x[sn * 36 + 24 + l];
        }

        // ---- B fragments: 5x ds_read_b128 (immediate offsets) ----
        const half8 B0 = *(const half8*)(rb + 0 * 512);
        const half8 B1 = *(const half8*)(rb + 1 * 512);
        const half8 B2 = *(const half8*)(rb + 2 * 512);
        const half8 B3 = *(const half8*)(rb + 3 * 512);
        const half8 B4 = *(const half8*)(rb + 4 * 512);

        // ---- Z~ = scaled(W)@[h;x;1] : 4 gate tiles x 5 K-tiles ----
        const f4 z = {0.f, 0.f, 0.f, 0.f};
        f4 ac0 = z, ac1 = z, ac2 = z, ac3 = z;
#pragma unroll
        for (int kt = 0; kt < 5; ++kt) {
            const half8 B = (kt == 0) ? B0 : (kt == 1) ? B1 : (kt == 2) ? B2
                          : (kt == 3) ? B3 : B4;
            ac0 = __builtin_amdgcn_mfma_f32_16x16x32_f16(A[0][kt], B, ac0, 0, 0, 0);
            ac1 = __builtin_amdgcn_mfma_f32_16x16x32_f16(A[1][kt], B, ac1, 0, 0, 0);
            ac2 = __builtin_amdgcn_mfma_f32_16x16x32_f16(A[2][kt], B, ac2, 0, 0, 0);
            ac3 = __builtin_amdgcn_mfma_f32_16x16x32_f16(A[3][kt], B, ac3, 0, 0, 0);
        }

        // ---- in-lane gates (scales pre-folded) + c/h update ----
        float h0, h1, h2, h3;
        {
            const float i0 = sigz(ac0[0]), f0 = sigz(ac1[0]);
            const float g0 = tanz(ac2[0]), o0 = sigz(ac3[0]);
            c0 = __builtin_fmaf(f0, c0, i0 * g0);  h0 = o0 * tanz(c0 * N2LOG2E);
            const float i1 = sigz(ac0[1]), f1 = sigz(ac1[1]);
            const float g1 = tanz(ac2[1]), o1 = sigz(ac3[1]);
            c1 = __builtin_fmaf(f1, c1, i1 * g1);  h1 = o1 * tanz(c1 * N2LOG2E);
            const float i2 = sigz(ac0[2]), f2 = sigz(ac1[2]);
            const float g2 = tanz(ac2[2]), o2 = sigz(ac3[2]);
            c2 = __builtin_fmaf(f2, c2, i2 * g2);  h2 = o2 * tanz(c2 * N2LOG2E);
            const float i3 = sigz(ac0[3]), f3 = sigz(ac1[3]);
            const float g3 = tanz(ac2[3]), o3 = sigz(ac3[3]);
            c3 = __builtin_fmaf(f3, c3, i3 * g3);  h3 = o3 * tanz(c3 * N2LOG2E);
        }

        // pack h (k ascending) and write in B-frag order (single b64)
        half4v hv;
        hv[0] = (_Float16)h0; hv[1] = (_Float16)h1;
        hv[2] = (_Float16)h2; hv[3] = (_Float16)h3;
        *(half4v*)(p ? wb0 : wb1) = hv;

        // ---- pout partials (R7-verified mechanism) ----
        half2v hp01, hp23;
        hp01[0] = hv[0]; hp01[1] = hv[1];
        hp23[0] = hv[2]; hp23[1] = hv[3];
        float pp = fdot2(hp23, wl23, fdot2(hp01, wl01, 0.0f));
        pp += __shfl_xor(pp, 16, 64);
        pp += __shfl_xor(pp, 32, 64);
        if (qk == 0) pout[p][n][w] = pp;

        // wave 7: combine LAST step's partials -> out ring (slot (s-1)&15)
        if (w == 7 && l < T_CH && s > 0) {
            const f4 pa = *(const f4*)&pout[p ^ 1][l][0];
            const f4 pb = *(const f4*)&pout[p ^ 1][l][4];
            oring[(s - 1) & 15][l] =
                pa.x + pa.y + pa.z + pa.w + pb.x + pb.y + pb.z + pb.w + blin;
        }

        // wave 5: flush rows [s-16, s-9] every 8 steps (slots disjoint from
        // wave 7's current slot: {0..7} vs 15, {8..15} vs 7)
        if (w == 5 && (s & 7) == 0 && s >= 16 && l < 24) {
            const int rbase = s - 16;
            const int slot  = rbase & 15;    // 0 or 8
            const float4 v = *(const float4*)((const float*)oring + slot * T_CH + 4 * l);
            *(float4*)(out + rbase * T_CH + 4 * l) = v;
        }

        // wave 0: publish x_{s+1} into the ext tile of buffer p^1
        if (w == 0 && l < T_CH) {
            _Float16* xd = p ? &hfrag[0][4][l][0] : &hfrag[1][4][l][0];
            half2v xp; xp[0] = (_Float16)xa; xp[1] = (_Float16)xb;
            *(half2v*)xd = xp;
            xd[2] = (_Float16)xc;
        }

        __syncthreads();
    }

    // ---- epilogue: out[S-1] into ring slot 15, then flush last 16 rows ----
    if (w == 7 && l < T_CH) {
        const int pb2 = (S_TOTAL - 1) & 1;
        const f4 pa = *(const f4*)&pout[pb2][l][0];
        const f4 pb = *(const f4*)&pout[pb2][l][4];
        oring[(S_TOTAL - 1) & 15][l] =
            pa.x + pa.y + pa.z + pa.w + pb.x + pb.y + pb.z + pb.w + blin;
    }
    __syncthreads();
    if (tid < 48) {   // rows S-16..S-1 = slots 0..15 in order (S%16==0)
        const float4 v = *(const float4*)((const float*)oring + 4 * tid);
        *(float4*)(out + (S_TOTAL - 16) * T_CH + 4 * tid) = v;
    }
}

extern "C" void kernel_launch(void* const* d_in, const int* in_sizes, int n_in,
                              void* d_out, int out_size, void* d_ws, size_t ws_size,
                              hipStream_t stream) {
    const float* x     = (const float*)d_in[0];
    const float* W_ih  = (const float*)d_in[1];
    const float* W_hh  = (const float*)d_in[2];
    const float* b_ih  = (const float*)d_in[3];
    const float* b_hh  = (const float*)d_in[4];
    const float* W_lin = (const float*)d_in[5];
    const float* b_lin = (const float*)d_in[6];
    float* out = (float*)d_out;

    hipLaunchKernelGGL(lstm_mfma, dim3(1), dim3(NT), 0, stream,
                       x, W_ih, W_hh, b_ih, b_hh, W_lin, b_lin, out);
}

// Round 12
// 16172.804 us; speedup vs baseline: 1.1939x; 1.1393x over previous
//
#include <hip/hip_runtime.h>

// Problem constants
#define S_TOTAL 19648      // B*N sequential LSTM steps
#define T_CH    12         // chains (MFMA N dim, padded to 16)
#define HID     128
#define NT      512        // 8 waves, one block (grid = 1) for the recurrence
#define WS_NEED ((size_t)S_TOTAL * 4096)   // h history: 4 KB/step fp16

typedef _Float16 half8  __attribute__((ext_vector_type(8)));
typedef _Float16 half4v __attribute__((ext_vector_type(4)));
typedef _Float16 half2v __attribute__((ext_vector_type(2)));
typedef float f4 __attribute__((ext_vector_type(4)));

#define NLOG2E  (-1.4426950408889634f)   // -log2(e): folded into i,f,o rows
#define N2LOG2E (-2.8853900817779268f)   // -2log2(e): folded into g rows

#if __has_builtin(__builtin_amdgcn_exp2f)
#define EXP2(x) __builtin_amdgcn_exp2f(x)
#else
#define EXP2(x) __expf((x) * 0.69314718055994531f)
#endif

__device__ __forceinline__ float sigz(float z) {   // z pre-scaled by -log2e
    return __builtin_amdgcn_rcpf(1.0f + EXP2(z));
}
__device__ __forceinline__ float tanz(float z) {   // z pre-scaled by -2log2e
    return __builtin_fmaf(2.0f, __builtin_amdgcn_rcpf(1.0f + EXP2(z)), -1.0f);
}
__device__ __forceinline__ float fdot2(half2v a, half2v b, float c) {
    return __builtin_amdgcn_fdot2(a, b, c, false);
}
#define MFMA(A, B, C) __builtin_amdgcn_mfma_f32_16x16x32_f16(A, B, C, 0, 0, 0)

// ---------------------------------------------------------------------------
// R11 post-mortem: VALU cut didn't move dur. Missing consumer = DS pipe
// (~600 cyc/step: 40x ds_read_b128 @12cyc + 16 ds_permute from the pout
// shuffles + pout/oring writes), phase-locked against VALU by the barrier.
// R12: (a) out-projection moved OUT of the loop — h history stored to d_ws
// (1-step-deferred coalesced 8B/lane stores; no drain stall), out computed
// by a parallel second kernel; deletes fdot2s/shuffles/pout/oring from the
// step. Host-side ws_size check picks this or the R11-proven pout fallback.
// (b) MFMA chains split 5->(3,2) (+f4 add) to shorten the serial head.
// (c) role work in the lgkm shadow; x pipelined 2 steps; unroll x2.
// ---------------------------------------------------------------------------
template<int USE_WS>
__global__ __launch_bounds__(NT, 2) void lstm_mfma(
    const float* __restrict__ x,      // (S,3,12): s*36 + f*12 + t
    const float* __restrict__ W_ih,   // (512,3)
    const float* __restrict__ W_hh,   // (512,128)
    const float* __restrict__ b_ih,   // (512)
    const float* __restrict__ b_hh,   // (512)
    const float* __restrict__ W_lin,  // (128)
    const float* __restrict__ b_lin,  // (1)
    float* __restrict__ out,          // (S,12): s*12 + t
    _Float16* __restrict__ hws)       // h history (USE_WS=1)
{
    const int tid = threadIdx.x;
    const int w   = tid >> 6;    // wave 0..7 -> j-tile base 16w
    const int l   = tid & 63;
    const int n   = l & 15;      // chain col; for A, l&15 is row m
    const int qk  = l >> 4;      // k-quad / row-quad

    // hfrag[buf][kt][lane][8 fp16]; kt=4 = ext tile (x0..x2, bias=1)
    __shared__ __align__(16) _Float16 hfrag[2][5][64][8];   // 10240 B
    __shared__ float pout[2][16][8];
    __shared__ __align__(16) float oring[16][T_CH];

    // ---- A fragments (fp16, activation scales folded) ----
    half8 A[4][5];
#pragma unroll
    for (int q = 0; q < 4; ++q) {
        const float sc = (q == 2) ? N2LOG2E : NLOG2E;
        const int row = q * HID + 16 * w + (l & 15);
#pragma unroll
        for (int kt = 0; kt < 4; ++kt) {
            const float* src = &W_hh[row * HID + kt * 32 + qk * 8];
            half8 a;
#pragma unroll
            for (int e = 0; e < 8; ++e) a[e] = (_Float16)(src[e] * sc);
            A[q][kt] = a;
        }
        half8 ae = {};
        if (qk == 0) {
            ae[0] = (_Float16)(W_ih[row * 3 + 0] * sc);
            ae[1] = (_Float16)(W_ih[row * 3 + 1] * sc);
            ae[2] = (_Float16)(W_ih[row * 3 + 2] * sc);
            ae[3] = (_Float16)((b_ih[row] + b_hh[row]) * sc);
        }
        A[q][4] = ae;
    }

    const int j0 = 16 * w + 4 * qk;
    half2v wl01, wl23;
    wl01[0] = (_Float16)W_lin[j0];     wl01[1] = (_Float16)W_lin[j0 + 1];
    wl23[0] = (_Float16)W_lin[j0 + 2]; wl23[1] = (_Float16)W_lin[j0 + 3];
    const float blin = b_lin[0];

    // ---- zero LDS; seed bias + x(s=0) ----
    ((uint4*)hfrag)[tid] = make_uint4(0, 0, 0, 0);
    if (tid < 128) ((uint4*)hfrag)[512 + tid] = make_uint4(0, 0, 0, 0);
    if (tid < 256) ((float*)pout)[tid] = 0.0f;
    __syncthreads();
    if (tid < 16) {
        hfrag[0][4][tid][3] = (_Float16)1.0f;
        hfrag[1][4][tid][3] = (_Float16)1.0f;
    }
    if (tid < T_CH) {
        hfrag[0][4][tid][0] = (_Float16)x[tid];
        hfrag[0][4][tid][1] = (_Float16)x[12 + tid];
        hfrag[0][4][tid][2] = (_Float16)x[24 + tid];
    }

    // ---- hoisted addresses ----
    const _Float16* rb0 = &hfrag[0][0][l][0];
    const _Float16* rb1 = &hfrag[1][0][l][0];
    const int ktw = w >> 1;
    const int lp  = (2 * (w & 1) + (qk >> 1)) * 16 + n;
    _Float16* wb0 = &hfrag[0][ktw][lp][4 * (qk & 1)];
    _Float16* wb1 = &hfrag[1][ktw][lp][4 * (qk & 1)];
    const int rec = w * 256 + l * 4;     // h-history record offset (halfs)

    float c0 = 0.f, c1 = 0.f, c2 = 0.f, c3 = 0.f;
    half4v hprev = {};                   // h_{s-1} kept in regs (USE_WS)

    // x pipeline: xn1 = x_{s+1}, xn2 = x_{s+2}
    float xn1a = 0.f, xn1b = 0.f, xn1c = 0.f;
    float xn2a = 0.f, xn2b = 0.f, xn2c = 0.f;
    if (w == 0 && l < T_CH) {
        xn1a = x[36 + l]; xn1b = x[48 + l]; xn1c = x[60 + l];
        xn2a = x[72 + l]; xn2b = x[84 + l]; xn2c = x[96 + l];
    }
    __syncthreads();

    auto step = [&](const int p, const int s) {
        const _Float16* rb = p ? rb1 : rb0;

        // ---- B-frag reads first (DS pipe starts); ext first ----
        const half8 B4 = *(const half8*)(rb + 4 * 512);
        const half8 B0 = *(const half8*)(rb + 0 * 512);
        const half8 B1 = *(const half8*)(rb + 1 * 512);
        const half8 B2 = *(const half8*)(rb + 2 * 512);
        const half8 B3 = *(const half8*)(rb + 3 * 512);

        // ---- shadow work (under the lgkm wait) ----
        if (USE_WS) {
            if (s > 0)   // store h_{s-1}: one coalesced b64/lane, ~full-step drain slack
                *(half4v*)(hws + (size_t)(s - 1) * 2048 + rec) = hprev;
        } else {
            // wave 7: combine step-(s-1) partials -> oring
            if (w == 7 && l < T_CH && s > 0) {
                const f4 pa = *(const f4*)&pout[p ^ 1][l][0];
                const f4 pb = *(const f4*)&pout[p ^ 1][l][4];
                oring[(s - 1) & 15][l] =
                    pa.x + pa.y + pa.z + pa.w + pb.x + pb.y + pb.z + pb.w + blin;
            }
            // wave 5: flush rows [s-16, s-9] (slots disjoint from wave 7's)
            if (w == 5 && (s & 7) == 0 && s >= 16 && l < 24) {
                const int rbase = s - 16;
                const int slot  = rbase & 15;
                const float4 v = *(const float4*)((const float*)oring + slot * T_CH + 4 * l);
                *(float4*)(out + rbase * T_CH + 4 * l) = v;
            }
        }
        // wave 0: publish x_{s+1} to ext tile of buffer p^1; rotate; load x_{s+3}
        if (w == 0 && l < T_CH) {
            _Float16* xd = p ? &hfrag[0][4][l][0] : &hfrag[1][4][l][0];
            half2v xp; xp[0] = (_Float16)xn1a; xp[1] = (_Float16)xn1b;
            *(half2v*)xd = xp;
            xd[2] = (_Float16)xn1c;
            xn1a = xn2a; xn1b = xn2b; xn1c = xn2c;
            const int sn = (s + 3 < S_TOTAL) ? (s + 3) : (S_TOTAL - 1);
            xn2a = x[sn * 36 + l];
            xn2b = x[sn * 36 + 12 + l];
            xn2c = x[sn * 36 + 24 + l];
        }

        // ---- MFMA, split chains (depth 3 + depth 2) ----
        const f4 z = {0.f, 0.f, 0.f, 0.f};
        f4 a0A = MFMA(A[0][4], B4, z), a1A = MFMA(A[1][4], B4, z);
        f4 a2A = MFMA(A[2][4], B4, z), a3A = MFMA(A[3][4], B4, z);
        f4 a0B = MFMA(A[0][2], B2, z), a1B = MFMA(A[1][2], B2, z);
        f4 a2B = MFMA(A[2][2], B2, z), a3B = MFMA(A[3][2], B2, z);
        a0A = MFMA(A[0][0], B0, a0A); a1A = MFMA(A[1][0], B0, a1A);
        a2A = MFMA(A[2][0], B0, a2A); a3A = MFMA(A[3][0], B0, a3A);
        a0B = MFMA(A[0][3], B3, a0B); a1B = MFMA(A[1][3], B3, a1B);
        a2B = MFMA(A[2][3], B3, a2B); a3B = MFMA(A[3][3], B3, a3B);
        a0A = MFMA(A[0][1], B1, a0A); a1A = MFMA(A[1][1], B1, a1A);
        a2A = MFMA(A[2][1], B1, a2A); a3A = MFMA(A[3][1], B1, a3A);
        const f4 ac0 = a0A + a0B, ac1 = a1A + a1B;
        const f4 ac2 = a2A + a2B, ac3 = a3A + a3B;

        // ---- gates (scales pre-folded) + c/h update ----
        float h0, h1, h2, h3;
        {
            const float i0 = sigz(ac0[0]), f0 = sigz(ac1[0]);
            const float g0 = tanz(ac2[0]), o0 = sigz(ac3[0]);
            c0 = __builtin_fmaf(f0, c0, i0 * g0);  h0 = o0 * tanz(c0 * N2LOG2E);
            const float i1 = sigz(ac0[1]), f1 = sigz(ac1[1]);
            const float g1 = tanz(ac2[1]), o1 = sigz(ac3[1]);
            c1 = __builtin_fmaf(f1, c1, i1 * g1);  h1 = o1 * tanz(c1 * N2LOG2E);
            const float i2 = sigz(ac0[2]), f2 = sigz(ac1[2]);
            const float g2 = tanz(ac2[2]), o2 = sigz(ac3[2]);
            c2 = __builtin_fmaf(f2, c2, i2 * g2);  h2 = o2 * tanz(c2 * N2LOG2E);
            const float i3 = sigz(ac0[3]), f3 = sigz(ac1[3]);
            const float g3 = tanz(ac2[3]), o3 = sigz(ac3[3]);
            c3 = __builtin_fmaf(f3, c3, i3 * g3);  h3 = o3 * tanz(c3 * N2LOG2E);
        }

        half4v hv;
        hv[0] = (_Float16)h0; hv[1] = (_Float16)h1;
        hv[2] = (_Float16)h2; hv[3] = (_Float16)h3;
        *(half4v*)(p ? wb0 : wb1) = hv;     // h_s in B-frag order

        if (USE_WS) {
            hprev = hv;
        } else {
            half2v hp01, hp23;
            hp01[0] = hv[0]; hp01[1] = hv[1];
            hp23[0] = hv[2]; hp23[1] = hv[3];
            float pp = fdot2(hp23, wl23, fdot2(hp01, wl01, 0.0f));
            pp += __shfl_xor(pp, 16, 64);
            pp += __shfl_xor(pp, 32, 64);
            if (qk == 0) pout[p][n][w] = pp;
        }
        __syncthreads();
    };

    for (int s = 0; s < S_TOTAL; s += 2) {
        step(0, s);
        step(1, s + 1);
    }

    // ---- epilogue ----
    if (USE_WS) {
        *(half4v*)(hws + (size_t)(S_TOTAL - 1) * 2048 + rec) = hprev;
    } else {
        if (w == 7 && l < T_CH) {
            const int pb2 = (S_TOTAL - 1) & 1;
            const f4 pa = *(const f4*)&pout[pb2][l][0];
            const f4 pb = *(const f4*)&pout[pb2][l][4];
            oring[(S_TOTAL - 1) & 15][l] =
                pa.x + pa.y + pa.z + pa.w + pb.x + pb.y + pb.z + pb.w + blin;
        }
        __syncthreads();
        if (tid < 48) {
            const float4 v = *(const float4*)((const float*)oring + 4 * tid);
            *(float4*)(out + (S_TOTAL - 16) * T_CH + 4 * tid) = v;
        }
    }
}

// Parallel out-projection: out[s,n] = h_s[:,n] . W_lin + b_lin
__global__ __launch_bounds__(256) void out_proj(
    const _Float16* __restrict__ hws,
    const float* __restrict__ W_lin,
    const float* __restrict__ b_lin,
    float* __restrict__ out)
{
    const int g = blockIdx.x * 256 + threadIdx.x;   // 0 .. S*12-1
    if (g >= S_TOTAL * T_CH) return;
    const int s = g / T_CH;
    const int n = g - s * T_CH;
    const _Float16* rc = hws + (size_t)s * 2048;
    float acc = 0.0f;
#pragma unroll
    for (int w = 0; w < 8; ++w)
#pragma unroll
        for (int qk = 0; qk < 4; ++qk) {
            // record of lane l = qk*16+n in wave w: 4 halfs, rows j0..j0+3
            const half4v hv = *(const half4v*)(rc + w * 256 + (qk * 16 + n) * 4);
            const int j = 16 * w + 4 * qk;
            acc += (float)hv[0] * W_lin[j]     + (float)hv[1] * W_lin[j + 1]
                 + (float)hv[2] * W_lin[j + 2] + (float)hv[3] * W_lin[j + 3];
        }
    out[g] = acc + b_lin[0];
}

extern "C" void kernel_launch(void* const* d_in, const int* in_sizes, int n_in,
                              void* d_out, int out_size, void* d_ws, size_t ws_size,
                              hipStream_t stream) {
    const float* x     = (const float*)d_in[0];
    const float* W_ih  = (const float*)d_in[1];
    const float* W_hh  = (const float*)d_in[2];
    const float* b_ih  = (const float*)d_in[3];
    const float* b_hh  = (const float*)d_in[4];
    const float* W_lin = (const float*)d_in[5];
    const float* b_lin = (const float*)d_in[6];
    float* out = (float*)d_out;
    _Float16* hws = (_Float16*)d_ws;

    if (ws_size >= WS_NEED) {   // constant across calls -> graph-safe
        hipLaunchKernelGGL((lstm_mfma<1>), dim3(1), dim3(NT), 0, stream,
                           x, W_ih, W_hh, b_ih, b_hh, W_lin, b_lin, out, hws);
        hipLaunchKernelGGL(out_proj, dim3((S_TOTAL * T_CH + 255) / 256), dim3(256),
                           0, stream, hws, W_lin, b_lin, out);
    } else {
        hipLaunchKernelGGL((lstm_mfma<0>), dim3(1), dim3(NT), 0, stream,
                           x, W_ih, W_hh, b_ih, b_hh, W_lin, b_lin, out, hws);
    }
}